// Round 6
// baseline (594.098 us; speedup 1.0000x reference)
//
#include <hip/hip_runtime.h>
#include <hip/hip_bf16.h>

// Problem: pooled = tanh(hs @ W^T + b); out0 = pooled[:,0]; out1 = span-means;
// out2 = zeros(N,S).  N=64, L=512, H=768, S=16. Inputs fp32, d_out fp32.
//
// R11: R9 skeleton (single dispatch, W-in-LDS once, zero-barrier K-loop,
// LDS-atomic epilogue -- R10 showed atomics are NOT the wall) with the
// latency-cover fix:
//  - BK=64 (NK=12): half as many wait events, 24 MFMAs behind each.
//  - A prefetch DISTANCE 2 in registers (areg[2] parity ring, k-loop fully
//    unrolled so all indexing is static): refills issued ~2 big iters
//    (~1200+ wall cyc at 4-wave share) before the consuming cvt. The loop
//    has NO barriers, so no vmcnt(0) drain ever flushes the prefetch.
//  - Iter-0/1 A-loads issued BEFORE the W-prologue stage (ride under it).
// Theory being tested: all pipes idle (Mfma 12%/VALU 17%/HBM 7%) because
// per-wave waits (lgkm on wf + vm on A at distance-1) serialize and all 4
// waves/SIMD stall at the same point; L2 is thrashed (4 passages x 1.5 MB
// = 6 MB > 4 MB/XCD) so A latency is often ~900 cyc.
#define NPASS 64
#define LSEQ  512
#define HDIM  768
#define NSPAN 16
#define OFF_SENT (NPASS*HDIM)                     // 49152
#define OFF_MASK (OFF_SENT + NPASS*NSPAN*HDIM)    // 835584

#define BN   96
#define NTN  6                     // BN/16 fragments per wave
#define BK   64
#define NK   (HDIM/BK)             // 12
#define NTILES (HDIM/BN)           // 8
#define NBLK (NPASS*NTILES)        // 512  (2 rounds on 256 CUs)
#define THREADS 1024
#define NMT  2                     // row-fragments per wave (32 rows/wave)

typedef __bf16 bf16x8 __attribute__((ext_vector_type(8)));
typedef __bf16 bf16x4 __attribute__((ext_vector_type(4)));
typedef float  f32x4  __attribute__((ext_vector_type(4)));

// tanh via v_exp_f32: ~7 VALU ops vs ~25 for libm tanhf. |err| < 1e-6 rel.
__device__ inline float fast_tanh(float x) {
  const float ax = fabsf(x);
  const float t  = __expf(-2.0f * ax);
  const float r  = (1.0f - t) * __builtin_amdgcn_rcpf(1.0f + t);
  return copysignf(r, x);
}

// 8x fp32 -> bf16x8 (RNE via fptrunc; compiler emits v_cvt_pk_bf16_f32 pairs).
__device__ inline bf16x8 cvt8(f32x4 lo, f32x4 hi) {
  union { bf16x4 h[2]; bf16x8 v; } u;
  u.h[0] = __builtin_convertvector(lo, bf16x4);
  u.h[1] = __builtin_convertvector(hi, bf16x4);
  return u.v;
}

__global__ __launch_bounds__(THREADS, 4) void fused_kernel(
    const float* __restrict__ A,        // (32768, 768) fp32
    const float* __restrict__ W,        // (768, 768) fp32, row o contiguous in h
    const float* __restrict__ bias,     // (768,)
    const int*   __restrict__ spans,    // (64,16,2)
    float* __restrict__ out)
{
  __shared__ __align__(16) unsigned short Wl[BN * HDIM];   // 147456 B bf16
  __shared__ float sent_lds[NSPAN][BN];                    // 6144 B
  __shared__ float inv_s[NSPAN];
  __shared__ float bias_s[BN];
  __shared__ short sid_l[LSEQ];                            // 1024 B
  // total ~155 KB -> 1 block/CU, 16 waves (4/SIMD)

  const int tid = threadIdx.x;
  const int b   = blockIdx.x;
  // XCD swizzle (bijective, 512 = 64*8): 8 sibling N-tiles of a passage land
  // consecutive on one XCD -> passage's 1.5 MB A-slice L2-shared.
  const int xcd = b & 7;
  const int t   = b >> 3;                 // 0..63 per XCD
  const int p   = ((t >> 3) << 3) | xcd;  // passage 0..63
  const int ntb = t & 7;                  // N-tile 0..7
  const int tile_n = ntb * BN;

  const int wave = tid >> 6;            // 0..15 -> rows [wave*32, wave*32+32)
  const int lane = tid & 63;
  const int quad = lane >> 4;
  const int lr   = lane & 15;

  // A-operand base: lane covers A[row = wave*32+mt*16+lr][quad*8 + ...].
  const float* Ab = A + ((size_t)p * LSEQ + wave * 32 + lr) * HDIM + quad * 8;

  // Distance-2 register prefetch ring. Indexed only by compile-time values
  // (k-loop fully unrolled) -> stays in VGPRs (rule: no runtime indexing).
  // areg[q][mt][kk*2+h] = f32x4 at row (mt*16), col k*BK + kk*32 + h*4.
  f32x4 areg[2][NMT][4];
  #define LOAD_A(q_, k_)                                                    \
    _Pragma("unroll")                                                       \
    for (int mt = 0; mt < NMT; ++mt) {                                      \
      const float* s_ = Ab + (size_t)mt * 16 * HDIM + (k_) * BK;            \
      _Pragma("unroll")                                                     \
      for (int kk = 0; kk < 2; ++kk) {                                      \
        areg[q_][mt][kk*2+0] = *(const f32x4*)(s_ + kk * 32);               \
        areg[q_][mt][kk*2+1] = *(const f32x4*)(s_ + kk * 32 + 4);           \
      }                                                                     \
    }

  // ---- Prologue ----
  // Issue iter-0/1 A-loads FIRST: they complete under the W-stage work.
  LOAD_A(0, 0)
  LOAD_A(1, 1)

  // Stage W slice: fp32 global -> cvt -> bf16 LDS, XOR-swizzled.
  // Layout: Wl[wr][kg'] with kg' = kg ^ (wr&7) over 16B granules (8 bf16).
  {
    const float* Wp = W + (size_t)tile_n * HDIM;
    #pragma unroll
    for (int j = 0; j < (BN * (HDIM / 8)) / THREADS; ++j) {
      const int g  = j * THREADS + tid;
      const int wr = g / (HDIM / 8);        // 0..95  (W row = output col)
      const int kg = g % (HDIM / 8);        // 0..95  (16B granule in K)
      const float* src = Wp + (size_t)wr * HDIM + kg * 8;
      const f32x4 lo = *(const f32x4*)src;
      const f32x4 hi = *(const f32x4*)(src + 4);
      const int kgs = kg ^ (wr & 7);
      *(bf16x8*)(Wl + (size_t)wr * HDIM + kgs * 8) = cvt8(lo, hi);
    }
  }

  // Span tables; sid_l for rows 0..511 (tid==row for tid<512).
  if (tid < LSEQ) {
    int st[NSPAN], en[NSPAN];
    #pragma unroll
    for (int i = 0; i < NSPAN; ++i) {
      st[i] = spans[(p * NSPAN + i) * 2 + 0];
      en[i] = spans[(p * NSPAN + i) * 2 + 1];
    }
    short s = -1;
    #pragma unroll
    for (int i = 0; i < NSPAN; ++i)
      if (tid >= st[i] && tid < en[i]) s = (short)i;
    sid_l[tid] = s;
  }
  if (tid < NSPAN)
    inv_s[tid] = 1.0f / (float)(spans[(p * NSPAN + tid) * 2 + 1] -
                                spans[(p * NSPAN + tid) * 2 + 0]);
  if (tid >= 512 && tid < 512 + BN) bias_s[tid - 512] = bias[tile_n + tid - 512];
  for (int i = tid; i < NSPAN * BN; i += THREADS) (&sent_lds[0][0])[i] = 0.f;

  __syncthreads();   // the ONLY barrier before the epilogue (drains prologue)

  f32x4 acc[NMT][NTN];
  #pragma unroll
  for (int mt = 0; mt < NMT; ++mt)
    #pragma unroll
    for (int nt = 0; nt < NTN; ++nt)
      acc[mt][nt] = (f32x4){0.f, 0.f, 0.f, 0.f};

  // ---- Zero-barrier K-loop, BK=64, prefetch distance 2 ----
  #pragma unroll
  for (int k = 0; k < NK; ++k) {
    const int q = k & 1;                  // compile-time after unroll

    // W fragments for both K=32 halves: Wl[wr=nt*16+lr][(4*ko+quad)^(lr&7)].
    bf16x8 wf[2][NTN];
    #pragma unroll
    for (int kk = 0; kk < 2; ++kk) {
      const int ko = k * 2 + kk;
      #pragma unroll
      for (int nt = 0; nt < NTN; ++nt) {
        const int wr = nt * 16 + lr;
        const int kg = (4 * ko + quad) ^ (lr & 7);
        wf[kk][nt] = *(const bf16x8*)(Wl + (size_t)wr * HDIM + kg * 8);
      }
    }

    // Consume areg[q] (loaded 2 iters ago; compiler emits counted vmcnt).
    bf16x8 abf[2][NMT];
    #pragma unroll
    for (int kk = 0; kk < 2; ++kk)
      #pragma unroll
      for (int mt = 0; mt < NMT; ++mt)
        abf[kk][mt] = cvt8(areg[q][mt][kk*2], areg[q][mt][kk*2+1]);

    // Refill the just-freed parity slot for iter k+2 (stays in flight
    // across the next ~2 full compute phases -- never force-drained).
    if (k + 2 < NK) { LOAD_A(q, k + 2) }

    __builtin_amdgcn_s_setprio(1);
    #pragma unroll
    for (int kk = 0; kk < 2; ++kk)
      #pragma unroll
      for (int mt = 0; mt < NMT; ++mt)
        #pragma unroll
        for (int nt = 0; nt < NTN; ++nt)
          acc[mt][nt] = __builtin_amdgcn_mfma_f32_16x16x32_bf16(
              abf[kk][mt], wf[kk][nt], acc[mt][nt], 0, 0, 0);
    __builtin_amdgcn_s_setprio(0);
  }

  // ---- Epilogue (R9's: run-merged LDS atomicAdd; R10 proved atomics are
  // not the wall and its staged version was slower). ----
  // C/D layout: col=lane&15, row=quad*4+reg (validated R3/R4).
  #pragma unroll
  for (int nt = 0; nt < NTN; ++nt) {
    const int col = nt * 16 + lr;            // 0..95
    const float bv = bias_s[col];
    #pragma unroll
    for (int mt = 0; mt < NMT; ++mt) {
      const int rowbase = wave * 32 + mt * 16 + quad * 4;   // local row
      int prev = -1; float run = 0.f;
      #pragma unroll
      for (int r = 0; r < 4; ++r) {
        const int row = rowbase + r;
        const float v = fast_tanh(acc[mt][nt][r] + bv);
        if (row == 0) out[(size_t)p * HDIM + tile_n + col] = v;  // pooled[:,0]
        const int s = sid_l[row];
        if (s != prev) {
          if (prev >= 0) atomicAdd(&sent_lds[prev][col], run);
          prev = s; run = 0.f;
        }
        run += v;
      }
      if (prev >= 0) atomicAdd(&sent_lds[prev][col], run);
    }
  }
  __syncthreads();

  // Writeout: sentence means + sentence_mask zeros.
  for (int i = tid; i < NSPAN * BN; i += THREADS) {
    const int s = i / BN, c = i % BN;
    out[OFF_SENT + ((size_t)p * NSPAN + s) * HDIM + tile_n + c] =
        sent_lds[s][c] * inv_s[s];
  }
  if (ntb == 0 && tid < NSPAN) out[OFF_MASK + p * NSPAN + tid] = 0.f;
}

extern "C" void kernel_launch(void* const* d_in, const int* in_sizes, int n_in,
                              void* d_out, int out_size, void* d_ws, size_t ws_size,
                              hipStream_t stream) {
  const float* hs  = (const float*)d_in[0];  // (64,512,768) fp32
  const float* w   = (const float*)d_in[1];  // (768,768) fp32
  const float* bsc = (const float*)d_in[2];  // (768,) fp32
  // d_in[3] attention_mask unused
  const int* spans = (const int*)d_in[4];    // (64,16,2) int32

  fused_kernel<<<dim3(NBLK), dim3(THREADS), 0, stream>>>(
      hs, w, bsc, spans, (float*)d_out);
}

// Round 7
// 281.058 us; speedup vs baseline: 2.1138x; 2.1138x over previous
//
#include <hip/hip_runtime.h>
#include <hip/hip_bf16.h>

// Problem: pooled = tanh(hs @ W^T + b); out0 = pooled[:,0]; out1 = span-means;
// out2 = zeros(N,S).  N=64, L=512, H=768, S=16. Inputs fp32, d_out fp32.
//
// R12: kill the A-re-read amplification. R8-R11 had 8 sibling blocks re-read
// each passage's 1.5 MB fp32 A-slice (6 MB concurrent/XCD > 4 MB L2 -> served
// by L3, invisible to every counter we collect). New decomposition:
//   block = 64 A-rows x ALL 768 cols  ->  A read EXACTLY ONCE (96 MB HBM).
//   W (2.4 MB, L2-resident) is the re-streamed operand: per K-iter stage
//   W-slice [768][32] bf16 (48 KB) + A-slice [64][32] fp32 (8 KB) into
//   double-buffered LDS via global_load_lds, R5-proven prefetch-then-drain.
//   512 thr / 8 waves, wave-tile 32x192: ~190 regs <= 256 budget @2 waves/SIMD
//   (R11 lesson: 1024-thr blocks cap at 128 and spill catastrophically).
//   Uniform 7 gload_lds per thread per stage (1 A seg + 6 W segs).
// Spans cross 64-row blocks -> pre-scaled global unsafeAtomicAdd (R5-proven)
// into memset-zeroed out. W pre-converted bf16 by tiny convert dispatch.
#define NPASS 64
#define LSEQ  512
#define HDIM  768
#define NSPAN 16
#define MTOT  (NPASS*LSEQ)                        // 32768
#define OFF_SENT (NPASS*HDIM)                     // 49152
#define OFF_MASK (OFF_SENT + NPASS*NSPAN*HDIM)    // 835584
#define W_ELEMS (HDIM*HDIM)                       // 589824

#define BM   64                    // A-rows per block
#define BK   32
#define NK   (HDIM/BK)             // 24
#define NBLK (MTOT/BM)             // 512 (2 rounds on 256 CUs)
#define THREADS 512
#define NMT  2                     // row frags per wave (32 rows)
#define NTN  12                    // col frags per wave (192 cols)

typedef __bf16 bf16x8 __attribute__((ext_vector_type(8)));
typedef __bf16 bf16x4 __attribute__((ext_vector_type(4)));
typedef float  f32x4  __attribute__((ext_vector_type(4)));

__device__ inline unsigned short f2bf(float f) {
  __hip_bfloat16 h = __float2bfloat16(f);   // RNE
  unsigned short u; __builtin_memcpy(&u, &h, 2); return u;
}

// tanh via v_exp_f32: ~7 VALU ops vs ~25 for libm tanhf. |err| < 1e-6 rel.
__device__ inline float fast_tanh(float x) {
  const float ax = fabsf(x);
  const float t  = __expf(-2.0f * ax);
  const float r  = (1.0f - t) * __builtin_amdgcn_rcpf(1.0f + t);
  return copysignf(r, x);
}

// 8x fp32 -> bf16x8 (RNE via fptrunc; compiler emits v_cvt_pk_bf16_f32 pairs).
__device__ inline bf16x8 cvt8(f32x4 lo, f32x4 hi) {
  union { bf16x4 h[2]; bf16x8 v; } u;
  u.h[0] = __builtin_convertvector(lo, bf16x4);
  u.h[1] = __builtin_convertvector(hi, bf16x4);
  return u.v;
}

// fp32 -> bf16 one-shot convert of W only. 8 elems/thread, 16B stores.
__global__ __launch_bounds__(256) void convert_w_kernel(
    const float* __restrict__ W, unsigned short* __restrict__ Wb)
{
  const int i = (blockIdx.x * 256 + threadIdx.x) * 8;
  const float4 a = *(const float4*)(W + i);
  const float4 b = *(const float4*)(W + i + 4);
  union { unsigned short us[8]; uint4 v; } o;
  o.us[0]=f2bf(a.x); o.us[1]=f2bf(a.y); o.us[2]=f2bf(a.z); o.us[3]=f2bf(a.w);
  o.us[4]=f2bf(b.x); o.us[5]=f2bf(b.y); o.us[6]=f2bf(b.z); o.us[7]=f2bf(b.w);
  *(uint4*)(Wb + i) = o.v;
}

__global__ __launch_bounds__(THREADS, 2) void gemm_fused_kernel(
    const float* __restrict__ A,              // (32768, 768) fp32
    const unsigned short* __restrict__ Wb,    // (768, 768) bf16
    const float* __restrict__ bias,
    const int* __restrict__ spans,
    float* __restrict__ out)
{
  __shared__ __align__(16) float          As[2][BM*BK];   // 2 x  8 KB fp32
  __shared__ __align__(16) unsigned short Ws[2][HDIM*BK]; // 2 x 48 KB bf16
  __shared__ float inv_s[NSPAN];
  __shared__ float bias_s[HDIM];                          // 3 KB
  __shared__ short sid_l[BM];
  // total ~116 KB -> 1 block/CU, 8 waves (2/SIMD), ~190 regs/wave OK

  const int tid  = threadIdx.x;
  const int b    = blockIdx.x;        // plain mapping: no A sharing anywhere
  const int p    = b >> 3;            // passage
  const int l0   = (b & 7) << 6;      // first local seq row
  const int row0 = b * BM;            // global A row

  const int wave = tid >> 6;          // 0..7
  const int lane = tid & 63;
  const int quad = lane >> 4;
  const int lr   = lane & 15;
  const int mr   = wave >> 2;         // 0..1: rows mr*32..+32
  const int nw   = wave & 3;          // 0..3: cols nw*192..+192

  // Stage K-slice k: 8 A segs (1/wave) + 48 W segs (6/wave) = 7 gload_lds
  // per thread, uniform. gload_lds dest is LINEAR (base + lane*16B); source
  // granule pre-XOR'd so LDS(row,g) holds global(row, g ^ f(row)):
  //   A (128 B rows, 8 granules): f = row&7  -> 2-way banked reads (free)
  //   W ( 64 B rows, 4 granules): f = row&3  -> 4-way banked reads (~1.6x,
  //     accepted: 4 slots is all a 64 B row offers under linear-dest)
  auto stage = [&](int k, int buf) {
    const int k0 = k * BK;
    {
      const int row = wave * 8 + (lane >> 3);
      const int g   = (lane & 7) ^ ((lane >> 3) & 7);
      const float* src = A + (size_t)(row0 + row) * HDIM + (k0 + g * 4);
      __builtin_amdgcn_global_load_lds(
          (const __attribute__((address_space(1))) void*)src,
          (__attribute__((address_space(3))) void*)(As[buf] + wave * 256),
          16, 0, 0);
    }
    #pragma unroll
    for (int j = 0; j < 6; ++j) {
      const int s2  = wave * 6 + j;            // 0..47
      const int row = s2 * 16 + (lane >> 2);   // 0..767 (W row = output col)
      const int g   = (lane & 3) ^ ((lane >> 2) & 3);
      const unsigned short* src = Wb + (size_t)row * HDIM + (k0 + g * 8);
      __builtin_amdgcn_global_load_lds(
          (const __attribute__((address_space(1))) void*)src,
          (__attribute__((address_space(3))) void*)(Ws[buf] + s2 * 512),
          16, 0, 0);
    }
  };

  // ---- Prologue ----
  stage(0, 0);
  if (tid < NSPAN)
    inv_s[tid] = 1.0f / (float)(spans[(p * NSPAN + tid) * 2 + 1] -
                                spans[(p * NSPAN + tid) * 2 + 0]);
  if (tid < BM) {
    const int l = l0 + tid;
    short s = -1;
    #pragma unroll
    for (int i = 0; i < NSPAN; ++i) {
      const int st = spans[(p * NSPAN + i) * 2 + 0];
      const int en = spans[(p * NSPAN + i) * 2 + 1];
      if (l >= st && l < en) s = (short)i;
    }
    sid_l[tid] = s;
  }
  for (int i = tid; i < HDIM; i += THREADS) bias_s[i] = bias[i];
  __syncthreads();   // drains stage(0), publishes tables

  f32x4 acc[NMT][NTN];
  #pragma unroll
  for (int mt = 0; mt < NMT; ++mt)
    #pragma unroll
    for (int nt = 0; nt < NTN; ++nt)
      acc[mt][nt] = (f32x4){0.f, 0.f, 0.f, 0.f};

  // ---- K-loop: prefetch-then-drain (R5-proven sync, race-free) ----
  for (int k = 0; k < NK; ++k) {
    const int cur = k & 1;
    if (k + 1 < NK) stage(k + 1, cur ^ 1);   // issue next slice first

    // A frags (fp32 -> bf16 at use): row = mr*32+mt*16+lr, granule XOR lr&7.
    bf16x8 abf[NMT];
    #pragma unroll
    for (int mt = 0; mt < NMT; ++mt) {
      const int row = mr * 32 + mt * 16 + lr;
      const float* base = As[cur] + row * BK;
      const f32x4 lo = *(const f32x4*)(base + (((quad * 2    ) ^ (lr & 7)) * 4));
      const f32x4 hi = *(const f32x4*)(base + (((quad * 2 + 1) ^ (lr & 7)) * 4));
      abf[mt] = cvt8(lo, hi);
    }
    // W frags: row = nw*192+nt*16+lr, granule quad ^ (lr&3).
    bf16x8 wf[NTN];
    #pragma unroll
    for (int nt = 0; nt < NTN; ++nt) {
      const int row = nw * 192 + nt * 16 + lr;
      wf[nt] = *(const bf16x8*)(Ws[cur] + row * BK + (quad ^ (lr & 3)) * 8);
    }

    __builtin_amdgcn_s_setprio(1);
    #pragma unroll
    for (int mt = 0; mt < NMT; ++mt)
      #pragma unroll
      for (int nt = 0; nt < NTN; ++nt)
        acc[mt][nt] = __builtin_amdgcn_mfma_f32_16x16x32_bf16(
            abf[mt], wf[nt], acc[mt][nt], 0, 0, 0);
    __builtin_amdgcn_s_setprio(0);

    // Drain + barrier: (a) everyone done reading buf cur before k+1 reuses
    // it; (b) vmcnt(0) covers the prefetch issued a full compute-phase ago.
    __syncthreads();
  }

  // ---- Epilogue: C/D layout col=lane&15, row=quad*4+reg (validated). ----
  // Span partials: run-merged, pre-scaled global atomics into zeroed out.
  #pragma unroll
  for (int nt = 0; nt < NTN; ++nt) {
    const int col = nw * 192 + nt * 16 + lr;       // 0..767
    const float bv = bias_s[col];
    float* sent_col = out + OFF_SENT + (size_t)(p * NSPAN) * HDIM + col;
    #pragma unroll
    for (int mt = 0; mt < NMT; ++mt) {
      const int rowbase = mr * 32 + mt * 16 + quad * 4;   // local row 0..63
      int prev = -1; float run = 0.f;
      #pragma unroll
      for (int r = 0; r < 4; ++r) {
        const int row = rowbase + r;
        const float v = fast_tanh(acc[mt][nt][r] + bv);
        if (l0 == 0 && row == 0) out[(size_t)p * HDIM + col] = v;  // pooled[:,0]
        const int s = sid_l[row];
        if (s != prev) {
          if (prev >= 0) unsafeAtomicAdd(sent_col + (size_t)prev * HDIM, run * inv_s[prev]);
          prev = s; run = 0.f;
        }
        run += v;
      }
      if (prev >= 0) unsafeAtomicAdd(sent_col + (size_t)prev * HDIM, run * inv_s[prev]);
    }
  }
  // sentence_mask zeros: covered by the memset.
}

extern "C" void kernel_launch(void* const* d_in, const int* in_sizes, int n_in,
                              void* d_out, int out_size, void* d_ws, size_t ws_size,
                              hipStream_t stream) {
  const float* hs  = (const float*)d_in[0];  // (64,512,768) fp32
  const float* w   = (const float*)d_in[1];  // (768,768) fp32
  const float* bsc = (const float*)d_in[2];  // (768,) fp32
  // d_in[3] attention_mask unused
  const int* spans = (const int*)d_in[4];    // (64,16,2) int32
  float* out = (float*)d_out;

  unsigned short* Wb = (unsigned short*)d_ws;  // 1,179,648 B

  hipMemsetAsync(d_out, 0, (size_t)out_size * sizeof(float), stream);

  convert_w_kernel<<<dim3(W_ELEMS / 8 / 256), dim3(256), 0, stream>>>(w, Wb);

  gemm_fused_kernel<<<dim3(NBLK), dim3(THREADS), 0, stream>>>(
      hs, Wb, bsc, spans, out);
}

// Round 8
// 270.792 us; speedup vs baseline: 2.1939x; 1.0379x over previous
//
#include <hip/hip_runtime.h>
#include <hip/hip_bf16.h>

// Problem: pooled = tanh(hs @ W^T + b); out0 = pooled[:,0]; out1 = span-means;
// out2 = zeros(N,S).  N=64, L=512, H=768, S=16. Inputs fp32, d_out fp32.
//
// R13: faithful port of the verified 256^2 8-phase schedule (T2+T3+T4+T5).
// Evidence: shallow variants all pin HBM at ~550 GB/s (wave stalls on operand
// arrival, in phase across waves); R7 (counted vmcnt) hit 2.1 TB/s but was a
// coarse split (m196's measured-negative config). The fine interleave is the
// only structure in the corpus proven to break this wall.
//   - BM=BN=256, BK=64, 512 thr / 8 waves (2M x 4N), per-wave out 128x64.
//   - 12 K-tiles x 4 phases; per phase: 12 swizzled ds_read_b128 || stage
//     (phases 0-1 issue ALL 8 half-tile loads of K-tile j+1 -> newest load
//     is >=2 phases old at the boundary) -> s_barrier -> setprio MFMA x16
//     -> [phase3: vmcnt(0)] -> s_barrier.  One vmcnt per K-tile, aged.
//   - LDS 128 KB: As/Bs[2 slots][2 halves][128x64] bf16, granule swizzle
//     g^(row&7) both-sides (pre-swizzled global src + swizzled ds_read):
//     64 lanes spread 8 granule-cols x 4 banks = conflict-free.
//   - A pre-converted bf16 (R5's convert kernel); R5's proven atomic epilogue.
// Race audit: slot s^1 written only after the boundary barrier ending all
// reads of it; slot s read only after vmcnt(0)+barrier retiring all writes.
#define NPASS 64
#define LSEQ  512
#define HDIM  768
#define NSPAN 16
#define MTOT  (NPASS*LSEQ)                     // 32768
#define OFF_SENT (NPASS*HDIM)                  // 49152
#define A_ELEMS (MTOT*HDIM)                    // 25165824
#define W_ELEMS (HDIM*HDIM)                    // 589824

#define BM 256
#define BN 256
#define BK 64
#define NKT (HDIM/BK)                          // 12 K-tiles
#define THREADS 512
#define NBLK ((MTOT/BM)*(HDIM/BN))             // 128*3 = 384

typedef __bf16 bf16x8 __attribute__((ext_vector_type(8)));
typedef float  f32x4  __attribute__((ext_vector_type(4)));

__device__ inline unsigned short f2bf(float f) {
  __hip_bfloat16 h = __float2bfloat16(f);   // RNE
  unsigned short u; __builtin_memcpy(&u, &h, 2); return u;
}

// tanh via v_exp_f32: ~7 VALU ops vs ~25 for libm tanhf. |err| < 1e-6 rel.
__device__ inline float fast_tanh(float x) {
  const float ax = fabsf(x);
  const float t  = __expf(-2.0f * ax);
  const float r  = (1.0f - t) * __builtin_amdgcn_rcpf(1.0f + t);
  return copysignf(r, x);
}

// fp32 -> bf16 one-shot convert of A then W (R5-verified). 8 elems/thread.
__global__ __launch_bounds__(256) void convert_kernel(
    const float* __restrict__ A, const float* __restrict__ W,
    unsigned short* __restrict__ Ab, unsigned short* __restrict__ Wb)
{
  const long long i = ((long long)blockIdx.x * 256 + threadIdx.x) * 8;
  const float* src; unsigned short* dst; long long off;
  if (i < A_ELEMS) { src = A; dst = Ab; off = i; }
  else             { src = W; dst = Wb; off = i - A_ELEMS; }
  const float4 a = *(const float4*)(src + off);
  const float4 b = *(const float4*)(src + off + 4);
  union { unsigned short us[8]; uint4 v; } o;
  o.us[0]=f2bf(a.x); o.us[1]=f2bf(a.y); o.us[2]=f2bf(a.z); o.us[3]=f2bf(a.w);
  o.us[4]=f2bf(b.x); o.us[5]=f2bf(b.y); o.us[6]=f2bf(b.z); o.us[7]=f2bf(b.w);
  *(uint4*)(dst + off) = o.v;
}

__global__ __launch_bounds__(THREADS, 2) void gemm_fused_kernel(
    const unsigned short* __restrict__ Ab,    // (32768, 768) bf16
    const unsigned short* __restrict__ Wb,    // (768, 768) bf16
    const float* __restrict__ bias,
    const int* __restrict__ spans,
    float* __restrict__ out)
{
  // [slot][half][128 rows x 64 cols bf16] = 16 KB per half-tile.
  __shared__ __align__(16) unsigned short As[2][2][128 * 64];   // 64 KB
  __shared__ __align__(16) unsigned short Bs[2][2][128 * 64];   // 64 KB
  __shared__ short sid_l[BM];
  __shared__ float inv_s[NSPAN];
  __shared__ float bias_s[BN];
  // ~130 KB -> 1 block/CU, 8 waves (2/SIMD, 256-reg budget)

  const int tid  = threadIdx.x;
  const int wave = tid >> 6;
  const int lane = tid & 63;
  const int quad = lane >> 4;
  const int lr   = lane & 15;
  const int wm   = wave >> 2;          // 0..1: row half (128 rows)
  const int wn   = wave & 3;           // 0..3: col quarter (64 cols)

  // Grid map: 3 N-sharers of an A-panel on the SAME XCD (b, b+128, b+256
  // all = b mod 8), 16 consecutive mblks per XCD per N-round. Bijective.
  const int b    = blockIdx.x;
  const int mblk = (b & 7) * 16 + ((b >> 3) & 15);
  const int nblk = b >> 7;
  const int tile_m = mblk * BM;
  const int tile_n = nblk * BN;
  const int p      = tile_m >> 9;      // passage (block is half a passage)
  const int l0     = tile_m & 511;     // 0 or 256

  // Stage one 16 KB half-tile: 2 gload_lds/thread. LDS dest LINEAR
  // (gi = l*512+tid -> per-(l,wave) uniform base + lane*16); global source
  // granule pre-swizzled g^(r&7) to match the swizzled ds_read (rule #21).
  auto stage_half = [&](const unsigned short* __restrict__ base_g, int row0g,
                        int j, int h, unsigned short* lds_half) {
    #pragma unroll
    for (int l = 0; l < 2; ++l) {
      const int gi = l * 512 + tid;
      const int r  = gi >> 3;
      const int g  = gi & 7;
      const unsigned short* src =
          base_g + (size_t)(row0g + h * 128 + r) * HDIM + j * BK + ((g ^ (r & 7)) * 8);
      __builtin_amdgcn_global_load_lds(
          (const __attribute__((address_space(1))) void*)src,
          (__attribute__((address_space(3))) void*)(lds_half + gi * 8),
          16, 0, 0);
    }
  };

  // ---- Prologue: stage K-tile 0 (all 4 halves) + tables, one drain. ----
  stage_half(Ab, tile_m, 0, 0, As[0][0]);
  stage_half(Ab, tile_m, 0, 1, As[0][1]);
  stage_half(Wb, tile_n, 0, 0, Bs[0][0]);
  stage_half(Wb, tile_n, 0, 1, Bs[0][1]);
  if (tid < BM) {
    const int l = l0 + tid;
    short s = -1;
    #pragma unroll
    for (int i = 0; i < NSPAN; ++i) {
      const int st = spans[(p * NSPAN + i) * 2 + 0];
      const int en = spans[(p * NSPAN + i) * 2 + 1];
      if (l >= st && l < en) s = (short)i;
    }
    sid_l[tid] = s;
  } else {
    bias_s[tid - 256] = bias[tile_n + tid - 256];
  }
  if (tid < NSPAN)
    inv_s[tid] = 1.0f / (float)(spans[(p * NSPAN + tid) * 2 + 1] -
                                spans[(p * NSPAN + tid) * 2 + 0]);
  __syncthreads();   // drains prologue stages (vmcnt 0) + publishes tables

  f32x4 acc[8][4];
  #pragma unroll
  for (int i = 0; i < 8; ++i)
    #pragma unroll
    for (int jj = 0; jj < 4; ++jj)
      acc[i][jj] = (f32x4){0.f, 0.f, 0.f, 0.f};

  // ---- Main loop: 12 K-tiles x 4 phases ----
  for (int j = 0; j < NKT; ++j) {
    const int s = j & 1;
    const unsigned short* Ah = As[s][wm];
    const unsigned short* Bh = Bs[s][wn >> 1];
    const int rbB = (wn & 1) * 64;             // B row base within its half

    #pragma unroll
    for (int ph = 0; ph < 4; ++ph) {
      const int qm = ph >> 1, qn = ph & 1;     // quadrant of wave's 128x64

      // Swizzled fragment reads (12 x ds_read_b128, conflict-free).
      bf16x8 af[4][2], bfr[2][2];
      #pragma unroll
      for (int mt = 0; mt < 4; ++mt) {
        const int r = qm * 64 + mt * 16 + lr;
        #pragma unroll
        for (int kk = 0; kk < 2; ++kk)
          af[mt][kk] = *(const bf16x8*)(Ah + (r * 8 + ((kk * 4 + quad) ^ (r & 7))) * 8);
      }
      #pragma unroll
      for (int nt = 0; nt < 2; ++nt) {
        const int r = rbB + qn * 32 + nt * 16 + lr;
        #pragma unroll
        for (int kk = 0; kk < 2; ++kk)
          bfr[nt][kk] = *(const bf16x8*)(Bh + (r * 8 + ((kk * 4 + quad) ^ (r & 7))) * 8);
      }

      // Stage K-tile j+1 into slot s^1: all 8 loads issued in phases 0-1 so
      // the newest is >=2 phases old at the boundary drain.
      if (j + 1 < NKT) {
        if (ph == 0) {
          stage_half(Ab, tile_m, j + 1, 0, As[s ^ 1][0]);
          stage_half(Ab, tile_m, j + 1, 1, As[s ^ 1][1]);
        } else if (ph == 1) {
          stage_half(Wb, tile_n, j + 1, 0, Bs[s ^ 1][0]);
          stage_half(Wb, tile_n, j + 1, 1, Bs[s ^ 1][1]);
        }
      }

      __builtin_amdgcn_s_barrier();            // phase lockstep (no drain)

      __builtin_amdgcn_s_setprio(1);
      #pragma unroll
      for (int mt = 0; mt < 4; ++mt)
        #pragma unroll
        for (int nt = 0; nt < 2; ++nt)
          #pragma unroll
          for (int kk = 0; kk < 2; ++kk)
            acc[qm * 4 + mt][qn * 2 + nt] = __builtin_amdgcn_mfma_f32_16x16x32_bf16(
                af[mt][kk], bfr[nt][kk], acc[qm * 4 + mt][qn * 2 + nt], 0, 0, 0);
      __builtin_amdgcn_s_setprio(0);

      // K-tile boundary: every wave retires its own 8 stage-loads (all aged
      // >= 2 phases) before the barrier -> slot s^1 complete for all waves.
      if (ph == 3) asm volatile("s_waitcnt vmcnt(0)" ::: "memory");
      __builtin_amdgcn_s_barrier();
    }
  }

  // ---- Epilogue (R5-proven): C/D col=lane&15, row=quad*4+reg. ----
  // Run-merged, pre-scaled global atomics into memset-zeroed out.
  #pragma unroll
  for (int ntg = 0; ntg < 4; ++ntg) {
    const int lcol = wn * 64 + ntg * 16 + lr;        // 0..255
    const int col  = tile_n + lcol;
    const float bv = bias_s[lcol];
    float* sent_col = out + OFF_SENT + (size_t)(p * NSPAN) * HDIM + col;
    #pragma unroll
    for (int mtg = 0; mtg < 8; ++mtg) {
      const int rowbase = wm * 128 + mtg * 16 + quad * 4;   // local row 0..255
      int prev = -1; float run = 0.f;
      #pragma unroll
      for (int r = 0; r < 4; ++r) {
        const int row = rowbase + r;
        const float v = fast_tanh(acc[mtg][ntg][r] + bv);
        if (l0 == 0 && row == 0) out[(size_t)p * HDIM + col] = v;  // pooled[:,0]
        const int sd = sid_l[row];
        if (sd != prev) {
          if (prev >= 0) unsafeAtomicAdd(sent_col + (size_t)prev * HDIM, run * inv_s[prev]);
          prev = sd; run = 0.f;
        }
        run += v;
      }
      if (prev >= 0) unsafeAtomicAdd(sent_col + (size_t)prev * HDIM, run * inv_s[prev]);
    }
  }
  // sentence_mask zeros: covered by the memset.
}

extern "C" void kernel_launch(void* const* d_in, const int* in_sizes, int n_in,
                              void* d_out, int out_size, void* d_ws, size_t ws_size,
                              hipStream_t stream) {
  const float* hs  = (const float*)d_in[0];  // (64,512,768) fp32
  const float* w   = (const float*)d_in[1];  // (768,768) fp32
  const float* bsc = (const float*)d_in[2];  // (768,) fp32
  // d_in[3] attention_mask unused
  const int* spans = (const int*)d_in[4];    // (64,16,2) int32
  float* out = (float*)d_out;

  unsigned short* Ab = (unsigned short*)d_ws;            // 50.3 MB
  unsigned short* Wb = Ab + A_ELEMS;                     // +1.2 MB

  hipMemsetAsync(d_out, 0, (size_t)out_size * sizeof(float), stream);

  convert_kernel<<<dim3((A_ELEMS + W_ELEMS) / 8 / 256), dim3(256), 0, stream>>>(
      hs, w, Ab, Wb);

  gemm_fused_kernel<<<dim3(NBLK), dim3(THREADS), 0, stream>>>(
      Ab, Wb, bsc, spans, out);
}

// Round 9
// 237.291 us; speedup vs baseline: 2.5037x; 1.1412x over previous
//
#include <hip/hip_runtime.h>
#include <hip/hip_bf16.h>

// Problem: pooled = tanh(hs @ W^T + b); out0 = pooled[:,0]; out1 = span-means;
// out2 = zeros(N,S).  N=64, L=512, H=768, S=16. Inputs fp32, d_out fp32.
//
// R14: traffic-targeted fix. Model closed in R8-R13 post-mortems:
//   R9's 120 us == 768 MB of A re-read traffic (8 N-tile siblings x 96 MB
//   fp32) through L3 at ~6.4 TB/s. Shallow-staged variants are issue-bound
//   instead. So: keep the free-running R8 structure, shrink the traffic.
//   - A pre-converted to bf16 (one convert dispatch, ~23 us): halves bytes,
//     A-frag load becomes ONE bf16x8 (exact MFMA fragment, no cvt).
//   - Concurrent working set per XCD = 4 passages x 768 KB bf16 = 3 MB
//     (+1.2 MB W) -> L2-resident (fp32 was 6 MB, thrashed). 7/8 re-reads
//     now L2-served; L3/HBM sees A ~once.
//   - 8 waves (wave = 64 rows x 96 cols, NMT=4): 24 MFMA per 6 identical
//     wf LDS reads -> low LDS-pipe pressure; acc 96 AGPR + ~70 VGPR fits
//     the 256-reg budget at 2 waves/SIMD.
//   - W[96x768] bf16 in LDS once (self ds_write, XOR-swizzled); zero-barrier
//     K-loop, prefetch-dist-1 A; LDS-atomic epilogue (self-contained, no
//     memset; R10 proved atomics are not a wall).
#define NPASS 64
#define LSEQ  512
#define HDIM  768
#define NSPAN 16
#define MTOT  (NPASS*LSEQ)                        // 32768
#define OFF_SENT (NPASS*HDIM)                     // 49152
#define OFF_MASK (OFF_SENT + NPASS*NSPAN*HDIM)    // 835584
#define A_ELEMS (MTOT*HDIM)                       // 25165824

#define BN   96
#define NTN  6                     // col frags per wave
#define BK   32
#define NK   (HDIM/BK)             // 24
#define NTILES (HDIM/BN)           // 8
#define NBLK (NPASS*NTILES)        // 512 (2 rounds on 256 CUs)
#define THREADS 512
#define NMT  4                     // row frags per wave (64 rows/wave)

typedef __bf16 bf16x8 __attribute__((ext_vector_type(8)));
typedef __bf16 bf16x4 __attribute__((ext_vector_type(4)));
typedef float  f32x4  __attribute__((ext_vector_type(4)));

__device__ inline unsigned short f2bf(float f) {
  __hip_bfloat16 h = __float2bfloat16(f);   // RNE
  unsigned short u; __builtin_memcpy(&u, &h, 2); return u;
}

// tanh via v_exp_f32: ~7 VALU ops vs ~25 for libm tanhf. |err| < 1e-6 rel.
__device__ inline float fast_tanh(float x) {
  const float ax = fabsf(x);
  const float t  = __expf(-2.0f * ax);
  const float r  = (1.0f - t) * __builtin_amdgcn_rcpf(1.0f + t);
  return copysignf(r, x);
}

// 8x fp32 -> bf16x8 (RNE via fptrunc; compiler emits v_cvt_pk_bf16_f32 pairs).
__device__ inline bf16x8 cvt8(f32x4 lo, f32x4 hi) {
  union { bf16x4 h[2]; bf16x8 v; } u;
  u.h[0] = __builtin_convertvector(lo, bf16x4);
  u.h[1] = __builtin_convertvector(hi, bf16x4);
  return u.v;
}

// fp32 -> bf16 one-shot convert of A. 8 elems/thread, 16B stores, coalesced.
__global__ __launch_bounds__(256) void convert_a_kernel(
    const float* __restrict__ A, unsigned short* __restrict__ Ab)
{
  const long long i = ((long long)blockIdx.x * 256 + threadIdx.x) * 8;
  const float4 a = *(const float4*)(A + i);
  const float4 b = *(const float4*)(A + i + 4);
  union { unsigned short us[8]; uint4 v; } o;
  o.us[0]=f2bf(a.x); o.us[1]=f2bf(a.y); o.us[2]=f2bf(a.z); o.us[3]=f2bf(a.w);
  o.us[4]=f2bf(b.x); o.us[5]=f2bf(b.y); o.us[6]=f2bf(b.z); o.us[7]=f2bf(b.w);
  *(uint4*)(Ab + i) = o.v;
}

__global__ __launch_bounds__(THREADS, 2) void fused_kernel(
    const unsigned short* __restrict__ Ab,  // (32768, 768) bf16
    const float* __restrict__ W,            // (768, 768) fp32
    const float* __restrict__ bias,         // (768,)
    const int*   __restrict__ spans,        // (64,16,2)
    float* __restrict__ out)
{
  __shared__ __align__(16) unsigned short Wl[BN * HDIM];   // 147456 B bf16
  __shared__ float sent_lds[NSPAN][BN];                    // 6144 B
  __shared__ float inv_s[NSPAN];
  __shared__ float bias_s[BN];
  __shared__ short sid_l[LSEQ];                            // 1024 B
  // total ~155 KB -> 1 block/CU, 8 waves (2/SIMD, 256-reg budget)

  const int tid = threadIdx.x;
  const int b   = blockIdx.x;
  // XCD swizzle: first concurrent round (b 0..255) puts, per XCD, 4 passages
  // x 8 N-tiles -> A working set 4 x 768 KB bf16 = 3 MB, L2-resident.
  const int xcd = b & 7;
  const int t   = b >> 3;                 // 0..63 per XCD
  const int p   = ((t >> 3) << 3) | xcd;  // passage 0..63
  const int ntb = t & 7;                  // N-tile 0..7
  const int tile_n = ntb * BN;

  // ---- Prologue ----

  // 1) Stage W slice: fp32 global -> cvt -> bf16 LDS, XOR-swizzled.
  //    Layout: Wl[wr][kg'] with kg' = kg ^ (wr&7) over 16B granules (8 bf16).
  //    9216 granules / 512 threads = 18 per thread, coalesced 32B loads.
  {
    const float* Wp = W + (size_t)tile_n * HDIM;
    #pragma unroll
    for (int j = 0; j < (BN * (HDIM / 8)) / THREADS; ++j) {
      const int g  = j * THREADS + tid;
      const int wr = g / (HDIM / 8);        // 0..95  (W row = output col)
      const int kg = g % (HDIM / 8);        // 0..95  (16B granule in K)
      const float* src = Wp + (size_t)wr * HDIM + kg * 8;
      const f32x4 lo = *(const f32x4*)src;
      const f32x4 hi = *(const f32x4*)(src + 4);
      const int kgs = kg ^ (wr & 7);
      *(bf16x8*)(Wl + (size_t)wr * HDIM + kgs * 8) = cvt8(lo, hi);
    }
  }

  // 2) Span tables; sid_l for rows 0..511 (tid==row).
  {
    int st[NSPAN], en[NSPAN];
    #pragma unroll
    for (int i = 0; i < NSPAN; ++i) {
      st[i] = spans[(p * NSPAN + i) * 2 + 0];
      en[i] = spans[(p * NSPAN + i) * 2 + 1];
    }
    short s = -1;
    #pragma unroll
    for (int i = 0; i < NSPAN; ++i)
      if (tid >= st[i] && tid < en[i]) s = (short)i;
    sid_l[tid] = s;
  }
  if (tid < NSPAN)
    inv_s[tid] = 1.0f / (float)(spans[(p * NSPAN + tid) * 2 + 1] -
                                spans[(p * NSPAN + tid) * 2 + 0]);
  if (tid < BN) bias_s[tid] = bias[tile_n + tid];
  for (int i = tid; i < NSPAN * BN; i += THREADS) (&sent_lds[0][0])[i] = 0.f;

  __syncthreads();   // the ONLY barrier before the epilogue

  // ---- Zero-barrier K-loop ----
  const int wave = tid >> 6;            // 0..7 -> rows [wave*64, wave*64+64)
  const int lane = tid & 63;
  const int quad = lane >> 4;
  const int lr   = lane & 15;

  // A-frag: lane holds Ab[row = wave*64+mt*16+lr][k*32 + quad*8 .. +8],
  // which IS the mfma_16x16x32 A-operand fragment (one bf16x8 load).
  const unsigned short* Abp =
      Ab + ((size_t)p * LSEQ + wave * 64 + lr) * HDIM + quad * 8;

  f32x4 acc[NMT][NTN];
  #pragma unroll
  for (int mt = 0; mt < NMT; ++mt)
    #pragma unroll
    for (int nt = 0; nt < NTN; ++nt)
      acc[mt][nt] = (f32x4){0.f, 0.f, 0.f, 0.f};

  bf16x8 a_cur[NMT], a_nxt[NMT];
  #pragma unroll
  for (int mt = 0; mt < NMT; ++mt)
    a_cur[mt] = *(const bf16x8*)(Abp + (size_t)mt * 16 * HDIM);

  #pragma unroll
  for (int k = 0; k < NK; ++k) {
    // W fragments: identical across waves (LDS serves from cache-like
    // banks; 6 b128 reads/wave/iter). Swizzle granule nt-independent.
    bf16x8 wf[NTN];
    #pragma unroll
    for (int nt = 0; nt < NTN; ++nt) {
      const int wr = nt * 16 + lr;
      const int kg = (4 * k + quad) ^ (lr & 7);
      wf[nt] = *(const bf16x8*)(Wl + (size_t)wr * HDIM + kg * 8);
    }
    // Prefetch next k (distance 1; A is L2-hot so ~200 cyc to cover).
    if (k + 1 < NK) {
      #pragma unroll
      for (int mt = 0; mt < NMT; ++mt)
        a_nxt[mt] = *(const bf16x8*)(Abp + (size_t)mt * 16 * HDIM + (k + 1) * BK);
    }
    __builtin_amdgcn_s_setprio(1);
    #pragma unroll
    for (int mt = 0; mt < NMT; ++mt)
      #pragma unroll
      for (int nt = 0; nt < NTN; ++nt)
        acc[mt][nt] = __builtin_amdgcn_mfma_f32_16x16x32_bf16(
            a_cur[mt], wf[nt], acc[mt][nt], 0, 0, 0);
    __builtin_amdgcn_s_setprio(0);
    #pragma unroll
    for (int mt = 0; mt < NMT; ++mt) a_cur[mt] = a_nxt[mt];
  }

  // ---- Epilogue: C/D layout col=lane&15, row=quad*4+reg (validated). ----
  // Span sums: run-merged LDS atomicAdd (block-local; scaled at writeout).
  #pragma unroll
  for (int nt = 0; nt < NTN; ++nt) {
    const int col = nt * 16 + lr;            // 0..95
    const float bv = bias_s[col];
    #pragma unroll
    for (int mt = 0; mt < NMT; ++mt) {
      const int rowbase = wave * 64 + mt * 16 + quad * 4;   // local row
      int prev = -1; float run = 0.f;
      #pragma unroll
      for (int r = 0; r < 4; ++r) {
        const int row = rowbase + r;
        const float v = fast_tanh(acc[mt][nt][r] + bv);
        if (row == 0) out[(size_t)p * HDIM + tile_n + col] = v;  // pooled[:,0]
        const int s = sid_l[row];
        if (s != prev) {
          if (prev >= 0) atomicAdd(&sent_lds[prev][col], run);
          prev = s; run = 0.f;
        }
        run += v;
      }
      if (prev >= 0) atomicAdd(&sent_lds[prev][col], run);
    }
  }
  __syncthreads();

  // Writeout: sentence means + sentence_mask zeros.
  for (int i = tid; i < NSPAN * BN; i += THREADS) {
    const int s = i / BN, c = i % BN;
    out[OFF_SENT + ((size_t)p * NSPAN + s) * HDIM + tile_n + c] =
        sent_lds[s][c] * inv_s[s];
  }
  if (ntb == 0 && tid < NSPAN) out[OFF_MASK + p * NSPAN + tid] = 0.f;
}

extern "C" void kernel_launch(void* const* d_in, const int* in_sizes, int n_in,
                              void* d_out, int out_size, void* d_ws, size_t ws_size,
                              hipStream_t stream) {
  const float* hs  = (const float*)d_in[0];  // (64,512,768) fp32
  const float* w   = (const float*)d_in[1];  // (768,768) fp32
  const float* bsc = (const float*)d_in[2];  // (768,) fp32
  // d_in[3] attention_mask unused
  const int* spans = (const int*)d_in[4];    // (64,16,2) int32

  unsigned short* Ab = (unsigned short*)d_ws;   // 50,331,648 B

  convert_a_kernel<<<dim3(A_ELEMS / 8 / 256), dim3(256), 0, stream>>>(hs, Ab);

  fused_kernel<<<dim3(NBLK), dim3(THREADS), 0, stream>>>(
      Ab, w, bsc, spans, (float*)d_out);
}

// Round 10
// 230.991 us; speedup vs baseline: 2.5720x; 1.0273x over previous
//
#include <hip/hip_runtime.h>
#include <hip/hip_bf16.h>

// Problem: pooled = tanh(hs @ W^T + b); out0 = pooled[:,0]; out1 = span-means;
// out2 = zeros(N,S).  N=64, L=512, H=768, S=16. Inputs fp32, d_out fp32.
//
// R15: R14 + close the L2-thrash gap. R14's wall closed quantitatively:
// 531 MB of cache traffic (A bf16 re-read 384 MB + W fp32 re-stage 147 MB)
// at 6.1 TB/s = 87 us = the L3 ceiling; per-XCD hot set 5.3 MB > 4 MB L2.
// This round:
//  - W pre-converted bf16 (convert dispatch does A+W): W hot set 2.3->1.2 MB,
//    per-XCD working set 4.2 MB ~ L2 -> A re-reads become L2-served.
//  - Persistent: 256 blocks (1/CU, ONE round), each does 2 passages with the
//    same N-tile -> W staged once per block, no second-round tail.
//  - W stage via global_load_lds (pre-swizzled source, rule #21), pure copy.
// K-loop / fragments / epilogue identical to R14 (verified).
#define NPASS 64
#define LSEQ  512
#define HDIM  768
#define NSPAN 16
#define MTOT  (NPASS*LSEQ)                        // 32768
#define OFF_SENT (NPASS*HDIM)                     // 49152
#define OFF_MASK (OFF_SENT + NPASS*NSPAN*HDIM)    // 835584
#define A_ELEMS (MTOT*HDIM)                       // 25165824
#define W_ELEMS (HDIM*HDIM)                       // 589824

#define BN   96
#define NTN  6                     // col frags per wave
#define BK   32
#define NK   (HDIM/BK)             // 24
#define NTILES (HDIM/BN)           // 8
#define NBLK 256                   // persistent: 1 block/CU, 2 passages each
#define THREADS 512
#define NMT  4                     // row frags per wave (64 rows/wave)

typedef __bf16 bf16x8 __attribute__((ext_vector_type(8)));
typedef __bf16 bf16x4 __attribute__((ext_vector_type(4)));
typedef float  f32x4  __attribute__((ext_vector_type(4)));

__device__ inline unsigned short f2bf(float f) {
  __hip_bfloat16 h = __float2bfloat16(f);   // RNE
  unsigned short u; __builtin_memcpy(&u, &h, 2); return u;
}

// tanh via v_exp_f32: ~7 VALU ops vs ~25 for libm tanhf. |err| < 1e-6 rel.
__device__ inline float fast_tanh(float x) {
  const float ax = fabsf(x);
  const float t  = __expf(-2.0f * ax);
  const float r  = (1.0f - t) * __builtin_amdgcn_rcpf(1.0f + t);
  return copysignf(r, x);
}

// fp32 -> bf16 one-shot convert of A then W. 8 elems/thread, 16B stores.
__global__ __launch_bounds__(256) void convert_kernel(
    const float* __restrict__ A, const float* __restrict__ W,
    unsigned short* __restrict__ Ab, unsigned short* __restrict__ Wb)
{
  const long long i = ((long long)blockIdx.x * 256 + threadIdx.x) * 8;
  const float* src; unsigned short* dst; long long off;
  if (i < A_ELEMS) { src = A; dst = Ab; off = i; }
  else             { src = W; dst = Wb; off = i - A_ELEMS; }
  const float4 a = *(const float4*)(src + off);
  const float4 b = *(const float4*)(src + off + 4);
  union { unsigned short us[8]; uint4 v; } o;
  o.us[0]=f2bf(a.x); o.us[1]=f2bf(a.y); o.us[2]=f2bf(a.z); o.us[3]=f2bf(a.w);
  o.us[4]=f2bf(b.x); o.us[5]=f2bf(b.y); o.us[6]=f2bf(b.z); o.us[7]=f2bf(b.w);
  *(uint4*)(dst + off) = o.v;
}

__global__ __launch_bounds__(THREADS, 2) void fused_kernel(
    const unsigned short* __restrict__ Ab,  // (32768, 768) bf16
    const unsigned short* __restrict__ Wb,  // (768, 768) bf16
    const float* __restrict__ bias,         // (768,)
    const int*   __restrict__ spans,        // (64,16,2)
    float* __restrict__ out)
{
  __shared__ __align__(16) unsigned short Wl[BN * HDIM];   // 147456 B bf16
  __shared__ float sent_lds[NSPAN][BN];                    // 6144 B
  __shared__ float inv_s[NSPAN];
  __shared__ float bias_s[BN];
  __shared__ short sid_l[LSEQ];                            // 1024 B
  // total ~155 KB -> 1 block/CU, 8 waves (2/SIMD, 256-reg budget)

  const int tid = threadIdx.x;
  const int b   = blockIdx.x;
  // XCD map: per XCD the 32 concurrent blocks = 4 passages x 8 N-tiles ->
  // hot set = 4 x 768 KB A-bf16 + 1.2 MB W-bf16 ~ 4.2 MB ~ L2.
  const int xcd = b & 7;
  const int t   = b >> 3;                 // 0..31 per XCD
  const int p0  = ((t >> 3) << 3) | xcd;  // first passage (0..31 range)
  const int ntb = t & 7;                  // N-tile 0..7
  const int tile_n = ntb * BN;

  const int wave = tid >> 6;            // 0..7 -> rows [wave*64, wave*64+64)
  const int lane = tid & 63;
  const int quad = lane >> 4;
  const int lr   = lane & 15;

  // ---- W stage (ONCE per block): bf16 copy via global_load_lds. ----
  // LDS linear granule gi = wr*96 + kg holds global granule kg ^ (wr&7)
  // (pre-swizzled source; reads use the same XOR -> rule #21 satisfied).
  {
    #pragma unroll
    for (int j = 0; j < (BN * (HDIM / 8)) / THREADS; ++j) {   // 18
      const int gi = j * THREADS + tid;
      const int wr = gi / (HDIM / 8);        // 0..95 (W row = output col)
      const int kg = gi % (HDIM / 8);        // 0..95 (16B granule in K)
      const unsigned short* src =
          Wb + (size_t)(tile_n + wr) * HDIM + ((kg ^ (wr & 7)) * 8);
      __builtin_amdgcn_global_load_lds(
          (const __attribute__((address_space(1))) void*)src,
          (__attribute__((address_space(3))) void*)(Wl + (size_t)gi * 8),
          16, 0, 0);
    }
  }
  if (tid < BN) bias_s[tid] = bias[tile_n + tid];

  // ---- Two passages per block, W/bias reused. ----
  for (int pi = 0; pi < 2; ++pi) {
    const int p = p0 + pi * 32;

    // Span tables; sid_l for rows 0..511 (tid==row). (pi=0: the following
    // barrier also drains the W gload_lds via its vmcnt(0).)
    {
      int st[NSPAN], en[NSPAN];
      #pragma unroll
      for (int i = 0; i < NSPAN; ++i) {
        st[i] = spans[(p * NSPAN + i) * 2 + 0];
        en[i] = spans[(p * NSPAN + i) * 2 + 1];
      }
      short s = -1;
      #pragma unroll
      for (int i = 0; i < NSPAN; ++i)
        if (tid >= st[i] && tid < en[i]) s = (short)i;
      sid_l[tid] = s;
    }
    if (tid < NSPAN)
      inv_s[tid] = 1.0f / (float)(spans[(p * NSPAN + tid) * 2 + 1] -
                                  spans[(p * NSPAN + tid) * 2 + 0]);
    for (int i = tid; i < NSPAN * BN; i += THREADS) (&sent_lds[0][0])[i] = 0.f;

    __syncthreads();   // tables + sent_lds zero published (+ W drain at pi=0)

    // ---- Zero-barrier K-loop (R14-identical) ----
    const unsigned short* Abp =
        Ab + ((size_t)p * LSEQ + wave * 64 + lr) * HDIM + quad * 8;

    f32x4 acc[NMT][NTN];
    #pragma unroll
    for (int mt = 0; mt < NMT; ++mt)
      #pragma unroll
      for (int nt = 0; nt < NTN; ++nt)
        acc[mt][nt] = (f32x4){0.f, 0.f, 0.f, 0.f};

    bf16x8 a_cur[NMT], a_nxt[NMT];
    #pragma unroll
    for (int mt = 0; mt < NMT; ++mt)
      a_cur[mt] = *(const bf16x8*)(Abp + (size_t)mt * 16 * HDIM);

    #pragma unroll
    for (int k = 0; k < NK; ++k) {
      bf16x8 wf[NTN];
      #pragma unroll
      for (int nt = 0; nt < NTN; ++nt) {
        const int wr = nt * 16 + lr;
        const int kg = (4 * k + quad) ^ (lr & 7);
        wf[nt] = *(const bf16x8*)(Wl + (size_t)wr * HDIM + kg * 8);
      }
      if (k + 1 < NK) {
        #pragma unroll
        for (int mt = 0; mt < NMT; ++mt)
          a_nxt[mt] = *(const bf16x8*)(Abp + (size_t)mt * 16 * HDIM + (k + 1) * BK);
      }
      __builtin_amdgcn_s_setprio(1);
      #pragma unroll
      for (int mt = 0; mt < NMT; ++mt)
        #pragma unroll
        for (int nt = 0; nt < NTN; ++nt)
          acc[mt][nt] = __builtin_amdgcn_mfma_f32_16x16x32_bf16(
              a_cur[mt], wf[nt], acc[mt][nt], 0, 0, 0);
      __builtin_amdgcn_s_setprio(0);
      #pragma unroll
      for (int mt = 0; mt < NMT; ++mt) a_cur[mt] = a_nxt[mt];
    }

    // ---- Epilogue (R14-identical): col=lane&15, row=quad*4+reg. ----
    #pragma unroll
    for (int nt = 0; nt < NTN; ++nt) {
      const int col = nt * 16 + lr;            // 0..95
      const float bv = bias_s[col];
      #pragma unroll
      for (int mt = 0; mt < NMT; ++mt) {
        const int rowbase = wave * 64 + mt * 16 + quad * 4;   // local row
        int prev = -1; float run = 0.f;
        #pragma unroll
        for (int r = 0; r < 4; ++r) {
          const int row = rowbase + r;
          const float v = fast_tanh(acc[mt][nt][r] + bv);
          if (row == 0) out[(size_t)p * HDIM + tile_n + col] = v;  // pooled[:,0]
          const int s = sid_l[row];
          if (s != prev) {
            if (prev >= 0) atomicAdd(&sent_lds[prev][col], run);
            prev = s; run = 0.f;
          }
          run += v;
        }
        if (prev >= 0) atomicAdd(&sent_lds[prev][col], run);
      }
    }
    __syncthreads();

    // Writeout: sentence means + sentence_mask zeros.
    for (int i = tid; i < NSPAN * BN; i += THREADS) {
      const int s = i / BN, c = i % BN;
      out[OFF_SENT + ((size_t)p * NSPAN + s) * HDIM + tile_n + c] =
          sent_lds[s][c] * inv_s[s];
    }
    if (ntb == 0 && tid < NSPAN) out[OFF_MASK + p * NSPAN + tid] = 0.f;

    __syncthreads();   // writeout done before next passage's table rewrite
  }
}

extern "C" void kernel_launch(void* const* d_in, const int* in_sizes, int n_in,
                              void* d_out, int out_size, void* d_ws, size_t ws_size,
                              hipStream_t stream) {
  const float* hs  = (const float*)d_in[0];  // (64,512,768) fp32
  const float* w   = (const float*)d_in[1];  // (768,768) fp32
  const float* bsc = (const float*)d_in[2];  // (768,) fp32
  // d_in[3] attention_mask unused
  const int* spans = (const int*)d_in[4];    // (64,16,2) int32

  unsigned short* Ab = (unsigned short*)d_ws;   // 50,331,648 B
  unsigned short* Wb = Ab + A_ELEMS;            // +1,179,648 B

  convert_kernel<<<dim3((A_ELEMS + W_ELEMS) / 8 / 256), dim3(256), 0, stream>>>(
      hs, w, Ab, Wb);

  fused_kernel<<<dim3(NBLK), dim3(THREADS), 0, stream>>>(
      Ab, Wb, bsc, spans, (float*)d_out);
}